// Round 5
// baseline (741.075 us; speedup 1.0000x reference)
//
#include <hip/hip_runtime.h>
#include <hip/hip_bf16.h>
#include <math.h>

#define BB 128
#define SS 256
#define HH 512
#define VV 50000
#define VEXT 50012
#define NBLK 782  // ceil(50000/64)

typedef __bf16 bf16x8 __attribute__((ext_vector_type(8)));
typedef float f32x4 __attribute__((ext_vector_type(4)));

__device__ __forceinline__ float fast_tanh(float x) {
  float e = __expf(2.0f * x);
  return 1.0f - 2.0f / (e + 1.0f);
}
__device__ __forceinline__ float fast_sigmoid(float x) {
  return 1.0f / (1.0f + __expf(-x));
}
__device__ __forceinline__ bf16x8 cvt8(const float* p) {
  float4 a = *(const float4*)p;
  float4 b = *(const float4*)(p + 4);
  bf16x8 r;
  r[0] = (__bf16)a.x; r[1] = (__bf16)a.y; r[2] = (__bf16)a.z; r[3] = (__bf16)a.w;
  r[4] = (__bf16)b.x; r[5] = (__bf16)b.y; r[6] = (__bf16)b.z; r[7] = (__bf16)b.w;
  return r;
}
__device__ __forceinline__ void omerge(float& M, float& S, float m2, float s2) {
  float Mn = fmaxf(M, m2);
  S = S * __expf(M - Mn) + s2 * __expf(m2 - Mn);
  M = Mn;
}

// ---- pack W rows into MFMA B-fragment order: dst[tile][ks][lane][8] bf16
__global__ void k_pack_w(const float* __restrict__ src, int ldw, int coff, int icount,
                         __hip_bfloat16* __restrict__ dst) {
  int i = blockIdx.x * 256 + threadIdx.x;
  if (i >= icount) return;
  int l = i & 63, ks = (i >> 6) & 15, tile = i >> 10;
  int m = l & 15, q = l >> 4;
  const float* p = src + (size_t)(tile * 16 + m) * ldw + coff + ks * 32 + q * 8;
  *(bf16x8*)(dst + (size_t)i * 8) = cvt8(p);
}

// ---- pack encoded into A-fragment order: dst[b][st][ks][lane][8]
__global__ void k_pack_enc(const float* __restrict__ enc, __hip_bfloat16* __restrict__ epk) {
  int i = blockIdx.x * 256 + threadIdx.x;  // 2097152
  int l = i & 63, ks = (i >> 6) & 15, st = (i >> 10) & 15, b = i >> 14;
  int m = l & 15, q = l >> 4;
  const float* p = enc + ((size_t)b * SS + st * 16 + m) * HH + ks * 32 + q * 8;
  *(bf16x8*)(epk + (size_t)i * 8) = cvt8(p);
}

// ---- pack y (128x1024 fp32) into A-fragment order: ypk[ks(32)][mt(8)][lane][8]
__global__ void k_pack_y(const float* __restrict__ y, __hip_bfloat16* __restrict__ ypk) {
  int i = blockIdx.x * 256 + threadIdx.x;  // 16384
  int l = i & 63, mt = (i >> 6) & 7, ks = i >> 9;
  int m = l & 15, q = l >> 4;
  const float* p = y + (size_t)(mt * 16 + m) * 1024 + ks * 32 + q * 8;
  *(bf16x8*)(ypk + (size_t)i * 8) = cvt8(p);
}

// ---- runtime-parameter MFMA GEMM body: C(128 x 64-tile) = A(128x512) @ B.T + bias
__device__ __forceinline__ void gemm_body(
    const float* __restrict__ A, const int* __restrict__ gidx, bool gather,
    const float* __restrict__ B, int ldb, const float* __restrict__ bias,
    float* __restrict__ C, int ldc, int blk, __hip_bfloat16* ylds) {
  const int t = threadIdx.x;
  const int l = t & 63, w = t >> 6;
  const int m = l & 15, q = l >> 4;
  const int n = blk * 64 + w * 16 + m;
  const float* wrow = B + (size_t)n * ldb;
  f32x4 acc[8];
#pragma unroll
  for (int mt = 0; mt < 8; ++mt) acc[mt] = (f32x4){0.f, 0.f, 0.f, 0.f};

  for (int kt = 0; kt < 512; kt += 64) {
    __syncthreads();
#pragma unroll
    for (int i = 0; i < 8; ++i) {
      int f = t + i * 256;
      int row = f >> 4, c4 = f & 15;
      const float* arow = gather ? A + (size_t)gidx[row] * 512 : A + (size_t)row * 512;
      float4 v = *(const float4*)(arow + kt + c4 * 4);
      __hip_bfloat16* d = ylds + row * 72 + c4 * 4;
      d[0] = __float2bfloat16(v.x); d[1] = __float2bfloat16(v.y);
      d[2] = __float2bfloat16(v.z); d[3] = __float2bfloat16(v.w);
    }
    __syncthreads();
#pragma unroll
    for (int ksl = 0; ksl < 2; ++ksl) {
      bf16x8 bfr = cvt8(wrow + kt + ksl * 32 + q * 8);
#pragma unroll
      for (int mt = 0; mt < 8; ++mt) {
        bf16x8 af = *(const bf16x8*)(ylds + (mt * 16 + m) * 72 + ksl * 32 + q * 8);
        acc[mt] = __builtin_amdgcn_mfma_f32_16x16x32_bf16(af, bfr, acc[mt], 0, 0, 0);
      }
    }
  }
  float bv = bias[n];
#pragma unroll
  for (int mt = 0; mt < 8; ++mt) {
#pragma unroll
    for (int r = 0; r < 4; ++r) {
      int rowm = mt * 16 + q * 4 + r;
      C[(size_t)rowm * ldc + n] = acc[mt][r] + bv;
    }
  }
}

// prevv (blocks 0-7) + gi (blocks 8-31) in one launch (independent)
__global__ __launch_bounds__(256, 2) void k_gemm_pg(
    const float* __restrict__ prev_state, const float* __restrict__ embed,
    const int* __restrict__ gidx, const float* __restrict__ Ws_w,
    const float* __restrict__ Ws_b, const float* __restrict__ gWih,
    const float* __restrict__ gbih, float* __restrict__ prevv, float* __restrict__ gi) {
  __shared__ __hip_bfloat16 ylds[128 * 72];
  if (blockIdx.x < 8)
    gemm_body(prev_state, nullptr, false, Ws_w, 512, Ws_b, prevv, 512, blockIdx.x, ylds);
  else
    gemm_body(embed, gidx, true, gWih, 1024, gbih, gi, 1536, blockIdx.x - 8, ylds);
}

__global__ __launch_bounds__(256, 2) void k_gemm_1(
    const float* __restrict__ A, const float* __restrict__ B, int ldb,
    const float* __restrict__ bias, float* __restrict__ C, int ldc) {
  __shared__ __hip_bfloat16 ylds[128 * 72];
  gemm_body(A, nullptr, false, B, ldb, bias, C, ldc, blockIdx.x, ylds);
}

// ---- GRU gates elementwise ----
__global__ void k_gates(const float* __restrict__ gi, const float* __restrict__ gh,
                        const float* __restrict__ prevv, float* __restrict__ state,
                        float* __restrict__ state_out) {
  int i = blockIdx.x * 256 + threadIdx.x;  // 65536
  int b = i >> 9, h = i & 511;
  const float* gib = gi + (size_t)b * 1536;
  const float* ghb = gh + (size_t)b * 1536;
  float ir = gib[h], iz = gib[512 + h], inn = gib[1024 + h];
  float hr = ghb[h], hz = ghb[512 + h], hn = ghb[1024 + h];
  float r = fast_sigmoid(ir + hr);
  float z = fast_sigmoid(iz + hz);
  float n = fast_tanh(inn + r * hn);
  float st = (1.f - z) * n + z * prevv[i];
  state[i] = st;
  state_out[i] = st;
}

// ---- fused MFMA kernel: out[b,s] = sum_n tanh(enc[b,s,:].W[n,:] + bias[n]) * mult[n]
template <int NTOT, int MODE>
__global__ __launch_bounds__(256, 3) void k_fused(
    const __hip_bfloat16* __restrict__ epack, const __hip_bfloat16* __restrict__ wpk,
    const float* __restrict__ biasA, const float* __restrict__ multA,
    const int* __restrict__ enc_idx, float* __restrict__ out) {
  const int b = blockIdx.x, s0 = blockIdx.y * 32, t = threadIdx.x;
  const int l = t & 63, w = t >> 6;
  const int wm = w & 1, wn = w >> 1;
  const int m = l & 15, q = l >> 4;
  __shared__ float bias_l[NTOT];
  __shared__ float mult_l[NTOT];
  __shared__ float red[2][32];
  const float* bias_base = (MODE == 0) ? biasA + (size_t)b * HH : biasA;
  const float* mult_base = (MODE == 0) ? multA : multA + (size_t)b * 1024;
  for (int i = t; i < NTOT; i += 256) {
    bias_l[i] = bias_base[i];
    mult_l[i] = mult_base[i];
  }
  const int st = blockIdx.y * 2 + wm;
  const __hip_bfloat16* ep = epack + ((size_t)(b * 16 + st) * 16) * 512 + (size_t)l * 8;
  bf16x8 afr[16];
#pragma unroll
  for (int ks = 0; ks < 16; ++ks) afr[ks] = *(const bf16x8*)(ep + ks * 512);
  __syncthreads();

  float part[4] = {0.f, 0.f, 0.f, 0.f};
  for (int nb = 0; nb < NTOT; nb += 32) {
    const __hip_bfloat16* wp = wpk + ((size_t)((nb >> 4) + wn) * 16) * 512 + (size_t)l * 8;
    bf16x8 bfr[16];
#pragma unroll
    for (int ks = 0; ks < 16; ++ks) bfr[ks] = *(const bf16x8*)(wp + ks * 512);
    f32x4 a0 = {0.f, 0.f, 0.f, 0.f}, a1 = a0, a2 = a0, a3 = a0;
#pragma unroll
    for (int j = 0; j < 4; ++j) {
      a0 = __builtin_amdgcn_mfma_f32_16x16x32_bf16(afr[j], bfr[j], a0, 0, 0, 0);
      a1 = __builtin_amdgcn_mfma_f32_16x16x32_bf16(afr[4 + j], bfr[4 + j], a1, 0, 0, 0);
      a2 = __builtin_amdgcn_mfma_f32_16x16x32_bf16(afr[8 + j], bfr[8 + j], a2, 0, 0, 0);
      a3 = __builtin_amdgcn_mfma_f32_16x16x32_bf16(afr[12 + j], bfr[12 + j], a3, 0, 0, 0);
    }
    f32x4 acc = (a0 + a1) + (a2 + a3);
    const int n = nb + wn * 16 + m;
    float bias = bias_l[n];
    float mul = mult_l[n];
#pragma unroll
    for (int r = 0; r < 4; ++r) part[r] += fast_tanh(acc[r] + bias) * mul;
  }
#pragma unroll
  for (int r = 0; r < 4; ++r) {
    part[r] += __shfl_xor(part[r], 1, 64);
    part[r] += __shfl_xor(part[r], 2, 64);
    part[r] += __shfl_xor(part[r], 4, 64);
    part[r] += __shfl_xor(part[r], 8, 64);
  }
  if (m == 0) {
#pragma unroll
    for (int r = 0; r < 4; ++r) red[wn][wm * 16 + q * 4 + r] = part[r];
  }
  __syncthreads();
  if (t < 32) {
    float v = red[0][t] + red[1][t];
    int s = s0 + t;
    if (MODE == 1 && enc_idx[b * SS + s] == 0) v -= 1000.0f;
    out[b * SS + s] = v;
  }
}

// ---- score_g v2: barrier-free, A from ypk (L2-hot), fused per-row online-softmax partials
__global__ __launch_bounds__(256, 2) void k_score_g2(
    const __hip_bfloat16* __restrict__ ypk, const float* __restrict__ Wo_w,
    const float* __restrict__ Wo_b, float* __restrict__ sg,
    float* __restrict__ gmax, float* __restrict__ gsum) {
  const int t = threadIdx.x;
  const int l = t & 63, w = t >> 6;
  const int m = l & 15, q = l >> 4;
  const int n = blockIdx.x * 64 + w * 16 + m;
  const int n_ld = (n < VV) ? n : (VV - 1);
  const float* wrow = Wo_w + (size_t)n_ld * 1024;
  f32x4 acc[8];
#pragma unroll
  for (int mt = 0; mt < 8; ++mt) acc[mt] = (f32x4){0.f, 0.f, 0.f, 0.f};
#pragma unroll 4
  for (int ks = 0; ks < 32; ++ks) {
    bf16x8 bfr = cvt8(wrow + ks * 32 + q * 8);
    const __hip_bfloat16* ab = ypk + (size_t)ks * 4096 + (size_t)l * 8;
#pragma unroll
    for (int mt = 0; mt < 8; ++mt) {
      bf16x8 af = *(const bf16x8*)(ab + mt * 512);
      acc[mt] = __builtin_amdgcn_mfma_f32_16x16x32_bf16(af, bfr, acc[mt], 0, 0, 0);
    }
  }
  const bool valid = (n < VV);
  float bias = valid ? Wo_b[n] : 0.f;
  __shared__ float smax[4 * 128];
  __shared__ float ssum[4 * 128];
#pragma unroll
  for (int mt = 0; mt < 8; ++mt) {
#pragma unroll
    for (int r = 0; r < 4; ++r) {
      float v = acc[mt][r] + bias;
      if (valid) sg[(size_t)(mt * 16 + q * 4 + r) * VV + n] = v;
      float vv = valid ? v : -1e30f;
      float M16 = vv;
      M16 = fmaxf(M16, __shfl_xor(M16, 1, 64));
      M16 = fmaxf(M16, __shfl_xor(M16, 2, 64));
      M16 = fmaxf(M16, __shfl_xor(M16, 4, 64));
      M16 = fmaxf(M16, __shfl_xor(M16, 8, 64));
      float e = valid ? __expf(vv - M16) : 0.f;
      e += __shfl_xor(e, 1, 64);
      e += __shfl_xor(e, 2, 64);
      e += __shfl_xor(e, 4, 64);
      e += __shfl_xor(e, 8, 64);
      if (m == 0) {
        smax[w * 128 + mt * 16 + q * 4 + r] = M16;
        ssum[w * 128 + mt * 16 + q * 4 + r] = e;
      }
    }
  }
  __syncthreads();
  if (t < 128) {
    float M = smax[t], S = ssum[t];
#pragma unroll
    for (int w2 = 1; w2 < 4; ++w2) omerge(M, S, smax[w2 * 128 + t], ssum[w2 * 128 + t]);
    gmax[(size_t)t * NBLK + blockIdx.x] = M;
    gsum[(size_t)t * NBLK + blockIdx.x] = S;
  }
}

// ---- attn softmax + context fused; assemble y = [state, context] ----
__global__ void k_softmax_ctx(const float* __restrict__ score, const float* __restrict__ enc,
                              const float* __restrict__ state, float* __restrict__ y) {
  const int b = blockIdx.x, t = threadIdx.x;  // 128 threads
  __shared__ float aws[SS];
  __shared__ float rb[4];
  float x0 = score[b * SS + t], x1 = score[b * SS + t + 128];
  float mx = fmaxf(x0, x1);
  for (int off = 32; off; off >>= 1) mx = fmaxf(mx, __shfl_xor(mx, off, 64));
  if ((t & 63) == 0) rb[t >> 6] = mx;
  __syncthreads();
  float M = fmaxf(rb[0], rb[1]);
  float e0 = __expf(x0 - M), e1 = __expf(x1 - M);
  float s = e0 + e1;
  for (int off = 32; off; off >>= 1) s += __shfl_xor(s, off, 64);
  if ((t & 63) == 0) rb[2 + (t >> 6)] = s;
  __syncthreads();
  float S = rb[2] + rb[3];
  aws[t] = e0 / S;
  aws[t + 128] = e1 / S;
  __syncthreads();
  float4 acc = {0.f, 0.f, 0.f, 0.f};
  const float* eb = enc + (size_t)b * SS * HH + t * 4;
#pragma unroll 4
  for (int s2 = 0; s2 < SS; ++s2) {
    float4 v = *(const float4*)(eb + (size_t)s2 * HH);
    acc.x += aws[s2] * v.x; acc.y += aws[s2] * v.y;
    acc.z += aws[s2] * v.z; acc.w += aws[s2] * v.w;
  }
  *(float4*)(y + (size_t)b * 1024 + HH + t * 4) = acc;
  *(float4*)(y + (size_t)b * 1024 + t * 4) = *(const float4*)(state + (size_t)b * HH + t * 4);
}

// ---- merge per-block partials + sc -> rmax/rsum (online softmax) ----
__global__ void k_rowstat_final(const float* __restrict__ gmax, const float* __restrict__ gsum,
                                const float* __restrict__ sc,
                                float* __restrict__ rmax, float* __restrict__ rsum) {
  const int b = blockIdx.x, t = threadIdx.x;  // 256
  __shared__ float wm[4], wsum[4];
  float M = -1e30f, S = 0.f;
  const float* gm = gmax + (size_t)b * NBLK;
  const float* gs = gsum + (size_t)b * NBLK;
  for (int i = t; i < NBLK; i += 256) omerge(M, S, gm[i], gs[i]);
  omerge(M, S, sc[b * SS + t], 1.0f);
  for (int off = 32; off; off >>= 1) {
    float Mo = __shfl_xor(M, off, 64), So = __shfl_xor(S, off, 64);
    omerge(M, S, Mo, So);
  }
  if ((t & 63) == 0) { wm[t >> 6] = M; wsum[t >> 6] = S; }
  __syncthreads();
  if (t == 0) {
    float Mf = wm[0], Sf = wsum[0];
    for (int i = 1; i < 4; ++i) omerge(Mf, Sf, wm[i], wsum[i]);
    rmax[b] = Mf;
    rsum[b] = Sf;
  }
}

__global__ void k_write_probg(const float* __restrict__ sg,
                              const float* __restrict__ rmax,
                              const float* __restrict__ rsum,
                              float* __restrict__ out) {
  int i = blockIdx.x * 256 + threadIdx.x;
  const int total = BB * VEXT;
  if (i >= total) return;
  int b = i / VEXT;
  int v = i - b * VEXT;
  float val;
  if (v < VV)
    val = __expf(sg[(size_t)b * VV + v] - rmax[b]) / rsum[b];
  else
    val = 1e-4f;
  out[i] = val;
}

__global__ void k_probc(const float* __restrict__ sc,
                        const int* __restrict__ enc_idx,
                        const float* __restrict__ rmax,
                        const float* __restrict__ rsum,
                        float* __restrict__ prob_c,
                        float* __restrict__ out,
                        float* __restrict__ pc_total) {
  const int b = blockIdx.x, t = threadIdx.x;
  __shared__ float rbuf[8];
  float pc = __expf(sc[b * SS + t] - rmax[b]) / rsum[b];
  prob_c[b * SS + t] = pc;
  atomicAdd(&out[(size_t)b * VEXT + enc_idx[b * SS + t]], pc);
  float s = pc;
  for (int off = 32; off > 0; off >>= 1) s += __shfl_down(s, off, 64);
  if ((t & 63) == 0) rbuf[t >> 6] = s;
  __syncthreads();
  if (t == 0) atomicAdd(pc_total, rbuf[0] + rbuf[1] + rbuf[2] + rbuf[3]);
}

// ---- weighted_new (float4 over all 512 h) ----
__global__ void k_weighted(const int* __restrict__ enc_idx,
                           const int* __restrict__ input_idx,
                           const float* __restrict__ prob_c,
                           const float* __restrict__ pc_total,
                           const float* __restrict__ enc,
                           float* __restrict__ wout) {
  const int b = blockIdx.x, t = threadIdx.x;  // 128 threads
  __shared__ float f[SS];
  __shared__ float rb[2];
  const int idx_in = input_idx[b];
  int m0 = (enc_idx[b * SS + t] == idx_in) ? 1 : 0;
  int m1 = (enc_idx[b * SS + t + 128] == idx_in) ? 1 : 0;
  float lsum = (float)(m0 + m1);
  for (int off = 32; off; off >>= 1) lsum += __shfl_xor(lsum, off, 64);
  if ((t & 63) == 0) rb[t >> 6] = lsum;
  __syncthreads();
  float tot = rb[0] + rb[1];
  float norm = (tot > 1.0f) ? 1.0f / tot : 1.0f;
  float ip = 1.0f / pc_total[0];
  f[t] = m0 ? prob_c[b * SS + t] * ip * norm : 0.f;
  f[t + 128] = m1 ? prob_c[b * SS + t + 128] * ip * norm : 0.f;
  __syncthreads();
  float4 acc = {0.f, 0.f, 0.f, 0.f};
  const float* eb = enc + (size_t)b * SS * HH + t * 4;
#pragma unroll 4
  for (int s2 = 0; s2 < SS; ++s2) {
    float4 v = *(const float4*)(eb + (size_t)s2 * HH);
    acc.x += f[s2] * v.x; acc.y += f[s2] * v.y;
    acc.z += f[s2] * v.z; acc.w += f[s2] * v.w;
  }
  *(float4*)(wout + (size_t)b * HH + t * 4) = acc;
}

extern "C" void kernel_launch(void* const* d_in, const int* in_sizes, int n_in,
                              void* d_out, int out_size, void* d_ws, size_t ws_size,
                              hipStream_t stream) {
  const int* input_idx = (const int*)d_in[0];
  const float* encoded = (const float*)d_in[1];
  const int* encoded_idx = (const int*)d_in[2];
  const float* prev_state = (const float*)d_in[3];
  const float* embed = (const float*)d_in[5];
  const float* Ws_w = (const float*)d_in[6];
  const float* Ws_b = (const float*)d_in[7];
  const float* gWih = (const float*)d_in[8];
  const float* gWhh = (const float*)d_in[9];
  const float* gbih = (const float*)d_in[10];
  const float* gbhh = (const float*)d_in[11];
  const float* attn_W = (const float*)d_in[12];
  const float* attn_b = (const float*)d_in[13];
  const float* attn_v = (const float*)d_in[14];
  const float* Wo_w = (const float*)d_in[15];
  const float* Wo_b = (const float*)d_in[16];
  const float* Wc_w = (const float*)d_in[17];
  const float* Wc_b = (const float*)d_in[18];

  float* out = (float*)d_out;
  float* out_state = out + (size_t)BB * VEXT;
  float* out_weighted = out_state + BB * HH;

  float* ws = (float*)d_ws;
  float* prevv = ws;                      // 65536
  float* state = prevv + BB * HH;         // 65536
  float* hW = state + BB * HH;            // 65536
  float* ascore = hW + BB * HH;           // 32768
  float* y = ascore + BB * SS;            // 131072
  float* sg = y + BB * 1024;              // 6400000 (gi/gh alias its head pre-score_g)
  float* sc = sg + (size_t)BB * VV;       // 32768
  float* prob_c = sc + BB * SS;           // 32768
  float* rmax = prob_c + BB * SS;         // 128
  float* rsum = rmax + BB;                // 128
  float* pc_total = rsum + BB;            // 64 (padded)
  float* gmax = pc_total + 64;            // 128*782 = 100096
  float* gsum = gmax + BB * NBLK;         // 100096
  __hip_bfloat16* ypk = (__hip_bfloat16*)(gsum + BB * NBLK);      // 131072 bf16
  __hip_bfloat16* wc_bf = ypk + 131072;                           // 1024*512 (packed)
  __hip_bfloat16* wa_bf = wc_bf + (size_t)1024 * HH;              // 512*512 (packed)
  __hip_bfloat16* epack = wa_bf + (size_t)512 * HH;               // 128*256*512 (packed)

  float* gi = sg;                  // 128*1536, dead before sg is written
  float* gh = sg + BB * 1536;      // 128*1536

  hipMemsetAsync(pc_total, 0, sizeof(float), stream);

  k_pack_w<<<256, 256, 0, stream>>>(Wc_w, 512, 0, 1024 * 64, wc_bf);
  k_pack_w<<<128, 256, 0, stream>>>(attn_W, 1024, 512, 512 * 64, wa_bf);
  k_pack_enc<<<8192, 256, 0, stream>>>(encoded, epack);

  // GRU chain via MFMA GEMMs (prevv + gi merged; gi independent of prevv)
  k_gemm_pg<<<32, 256, 0, stream>>>(prev_state, embed, input_idx, Ws_w, Ws_b,
                                    gWih, gbih, prevv, gi);
  k_gemm_1<<<24, 256, 0, stream>>>(prevv, gWhh, 512, gbhh, gh, 1536);
  k_gates<<<256, 256, 0, stream>>>(gi, gh, prevv, state, out_state);
  k_gemm_1<<<8, 256, 0, stream>>>(state, attn_W, 1024, attn_b, hW, 512);

  k_fused<HH, 0><<<dim3(BB, 8), 256, 0, stream>>>(epack, wa_bf, hW, attn_v,
                                                  nullptr, ascore);
  k_softmax_ctx<<<BB, 128, 0, stream>>>(ascore, encoded, state, y);
  k_pack_y<<<64, 256, 0, stream>>>(y, ypk);

  k_score_g2<<<NBLK, 256, 0, stream>>>(ypk, Wo_w, Wo_b, sg, gmax, gsum);
  k_fused<1024, 1><<<dim3(BB, 8), 256, 0, stream>>>(epack, wc_bf, Wc_b, y,
                                                    encoded_idx, sc);

  k_rowstat_final<<<BB, 256, 0, stream>>>(gmax, gsum, sc, rmax, rsum);
  k_write_probg<<<(BB * VEXT + 255) / 256, 256, 0, stream>>>(sg, rmax, rsum, out);
  k_probc<<<BB, 256, 0, stream>>>(sc, encoded_idx, rmax, rsum, prob_c, out, pc_total);
  k_weighted<<<BB, 128, 0, stream>>>(encoded_idx, input_idx, prob_c, pc_total,
                                     encoded, out_weighted);
}